// Round 2
// baseline (6425.164 us; speedup 1.0000x reference)
//
#include <hip/hip_runtime.h>
#include <math.h>

#define BDIM 8
#define FR   257
#define TT   300
#define CC   64
#define NN   (BDIM*TT)      // 2400
#define CPPC 16
#define GG   8
#define CPG  8              // CC/GG
#define KW   3
#define EPSV 1e-5f

#define FT    65            // inner rows per F-tile
#define NTIL  4             // ceil(257/65)
#define ROWS  67            // FT + 2 halo
#define RPW   17            // ceil(ROWS/4) rows per wave
#define FSTR  68            // padded LDS row stride (floats): 16B-aligned, 2-way banks

#define X1_ELEMS ((size_t)NN*FR*CC)     // 39,475,200
#define HP_ELEMS ((size_t)CPPC*NN*FR)   //  9,868,800

__device__ __forceinline__ void ln_stats(float v, float& m, float& r) {
    float s = v, ss = v*v;
    #pragma unroll
    for (int off = 32; off > 0; off >>= 1) {
        s  += __shfl_xor(s,  off, 64);
        ss += __shfl_xor(ss, off, 64);
    }
    m = s * (1.0f/64.0f);
    float var = ss * (1.0f/64.0f) - m*m;
    r = rsqrtf(var + EPSV);
}

// ---------------- Kernel 1: freq_conv1 + LN2 + reduce + silu (F-tiled) ----------------
__global__ __launch_bounds__(256, 4)
void k_fc1(const float* __restrict__ h,
           const float* __restrict__ g1, const float* __restrict__ b1,
           const float* __restrict__ w1, const float* __restrict__ cb1,
           const float* __restrict__ a1,
           const float* __restrict__ g2, const float* __restrict__ b2,
           const float* __restrict__ redw, const float* __restrict__ redb,
           float* __restrict__ x1, float* __restrict__ hpT)
{
    __shared__ __align__(16) float ys[ROWS*FSTR];
    __shared__ __align__(16) float rw[CPPC*CC];

    const int n  = blockIdx.x;
    const int f0 = blockIdx.y * FT;
    const int b = n / TT, t = n - b*TT;
    const int tid = threadIdx.x;
    const int lane = tid & 63, wid = tid >> 6;

    float wreg[CPG][KW];
    #pragma unroll
    for (int i = 0; i < CPG; ++i)
        #pragma unroll
        for (int k = 0; k < KW; ++k)
            wreg[i][k] = w1[lane*CPG*KW + i*KW + k];
    const float alpha = a1[0];
    const float gA = g1[lane], bA = b1[lane];
    const float gB = g2[lane], bB = b2[lane];
    const float cbv = cb1[lane];

    for (int e = tid; e < CPPC*CC; e += 256) rw[e] = redw[e];

    // load rows (halo included) + LN1 -> ys; residual x kept in registers
    float xreg[RPW];
    const size_t hb0 = ((size_t)b*FR*TT + t)*CC;
    #pragma unroll
    for (int it = 0; it < RPW; ++it) {
        int lr = wid + it*4;
        int f  = f0 - 1 + lr;
        xreg[it] = 0.0f;
        if (lr < ROWS && f >= 0 && f < FR) {
            float v = h[hb0 + (size_t)f*TT*CC + lane];
            xreg[it] = v;
            float m, r; ln_stats(v, m, r);
            ys[lr*FSTR + lane] = (v - m) * r * gA + bA;
        }
    }
    __syncthreads();

    // grouped conv over F (K=3) + PReLU + residual (inner rows only); x2 -> xreg, x1 global
    const int gi = (lane >> 3) * CPG;
    #pragma unroll
    for (int it = 0; it < RPW; ++it) {
        int lr = wid + it*4;
        int f  = f0 - 1 + lr;
        if (lr >= 1 && lr <= FT && f < FR) {
            float acc = cbv;
            if (f - 1 >= 0) {
                #pragma unroll
                for (int i = 0; i < CPG; ++i) acc += ys[(lr-1)*FSTR + gi + i] * wreg[i][0];
            }
            #pragma unroll
            for (int i = 0; i < CPG; ++i) acc += ys[lr*FSTR + gi + i] * wreg[i][1];
            if (f + 1 < FR) {
                #pragma unroll
                for (int i = 0; i < CPG; ++i) acc += ys[(lr+1)*FSTR + gi + i] * wreg[i][2];
            }
            float pr = acc >= 0.0f ? acc : alpha*acc;
            float xv = xreg[it] + pr;
            xreg[it] = xv;
            x1[(size_t)n*FR*CC + (size_t)f*CC + lane] = xv;
        }
    }
    __syncthreads();   // all conv reads of ys done

    // LN2 (full-band LN) on inner rows -> ys
    #pragma unroll
    for (int it = 0; it < RPW; ++it) {
        int lr = wid + it*4;
        int f  = f0 - 1 + lr;
        if (lr >= 1 && lr <= FT && f < FR) {
            float v = xreg[it];
            float m, r; ln_stats(v, m, r);
            ys[lr*FSTR + lane] = (v - m) * r * gB + bB;
        }
    }
    __syncthreads();

    // reduce: hp[p, f] = silu( sum_c ys[f,c]*rw[p,c] + rb[p] ) -> hpT[p][n][f]
    const int nf = min(FT, FR - f0);  // inner rows in this tile
    for (int idx = tid; idx < CPPC*FT; idx += 256) {
        int p = idx / FT, fi = idx - p*FT;
        if (fi >= nf) continue;
        int lr = fi + 1;
        float acc = redb[p];
        const float4* yrow = reinterpret_cast<const float4*>(&ys[lr*FSTR]);
        const float4* wrow = reinterpret_cast<const float4*>(&rw[p*CC]);
        #pragma unroll
        for (int c4 = 0; c4 < CC/4; ++c4) {
            float4 y = yrow[c4], w = wrow[c4];
            acc += y.x*w.x + y.y*w.y + y.z*w.z + y.w*w.w;
        }
        float sg = acc / (1.0f + expf(-acc));
        hpT[(size_t)p*(NN*FR) + (size_t)n*FR + (f0 + fi)] = sg;
    }
}

// ---------------- Kernel 2: 16 batched GEMMs  out[n,f'] = sum_f A[n,f]*B[f',f] ----------------
#define BM 64
#define BN 64
#define BK 32
#define LDT 72

__global__ __launch_bounds__(256, 4)
void k_fgemm(const float* __restrict__ hpT, const float* __restrict__ fW,
             const float* __restrict__ fB, float* __restrict__ hp2T)
{
    __shared__ __align__(16) float As[BK*LDT];
    __shared__ __align__(16) float Bs[BK*LDT];
    const int c  = blockIdx.z;
    const int m0 = blockIdx.x * BM;
    const int f0 = blockIdx.y * BN;
    const int tid = threadIdx.x;
    const int tm = tid & 15, tn = tid >> 4;

    const float* Ab = hpT + (size_t)c*(NN*FR);
    const float* Bb = fW  + (size_t)c*(FR*FR);

    float acc[4][4];
    #pragma unroll
    for (int i = 0; i < 4; ++i)
        #pragma unroll
        for (int j = 0; j < 4; ++j) acc[i][j] = 0.0f;

    for (int k0 = 0; k0 < FR; k0 += BK) {
        #pragma unroll
        for (int l = 0; l < 8; ++l) {
            int e = tid + l*256;
            int r = e >> 5, kc = e & 31;
            int m = m0 + r, k = k0 + kc;
            As[kc*LDT + r] = (m < NN && k < FR) ? Ab[(size_t)m*FR + k] : 0.0f;
            int fr = f0 + r;
            Bs[kc*LDT + r] = (fr < FR && k < FR) ? Bb[(size_t)fr*FR + k] : 0.0f;
        }
        __syncthreads();
        #pragma unroll
        for (int k = 0; k < BK; ++k) {
            const float4 av = *reinterpret_cast<const float4*>(&As[k*LDT + (tm<<2)]);
            const float4 bv = *reinterpret_cast<const float4*>(&Bs[k*LDT + (tn<<2)]);
            acc[0][0] += av.x*bv.x; acc[0][1] += av.x*bv.y; acc[0][2] += av.x*bv.z; acc[0][3] += av.x*bv.w;
            acc[1][0] += av.y*bv.x; acc[1][1] += av.y*bv.y; acc[1][2] += av.y*bv.z; acc[1][3] += av.y*bv.w;
            acc[2][0] += av.z*bv.x; acc[2][1] += av.z*bv.y; acc[2][2] += av.z*bv.z; acc[2][3] += av.z*bv.w;
            acc[3][0] += av.w*bv.x; acc[3][1] += av.w*bv.y; acc[3][2] += av.w*bv.z; acc[3][3] += av.w*bv.w;
        }
        __syncthreads();
    }

    #pragma unroll
    for (int i = 0; i < 4; ++i) {
        int m = m0 + (tm<<2) + i;
        if (m >= NN) continue;
        #pragma unroll
        for (int j = 0; j < 4; ++j) {
            int fr = f0 + (tn<<2) + j;
            if (fr < FR)
                hp2T[(size_t)c*(NN*FR) + (size_t)m*FR + fr] = acc[i][j] + fB[c*FR + fr];
        }
    }
}

// ---------------- Kernel 3: expand + silu + residual + LN + freq_conv2 (F-tiled) ----------------
__global__ __launch_bounds__(256, 4)
void k_fc2(const float* __restrict__ x1, const float* __restrict__ hp2T,
           const float* __restrict__ expw, const float* __restrict__ expb,
           const float* __restrict__ g3, const float* __restrict__ b3,
           const float* __restrict__ w2, const float* __restrict__ cb2,
           const float* __restrict__ a2,
           float* __restrict__ out)
{
    __shared__ __align__(16) float ys[ROWS*FSTR];
    __shared__ float hb[CPPC*FSTR];

    const int n  = blockIdx.x;
    const int f0 = blockIdx.y * FT;
    const int b = n / TT, t = n - b*TT;
    const int tid = threadIdx.x;
    const int lane = tid & 63, wid = tid >> 6;

    float wreg[CPG][KW];
    #pragma unroll
    for (int i = 0; i < CPG; ++i)
        #pragma unroll
        for (int k = 0; k < KW; ++k)
            wreg[i][k] = w2[lane*CPG*KW + i*KW + k];
    float ew[CPPC];
    #pragma unroll
    for (int p = 0; p < CPPC; ++p) ew[p] = expw[lane*CPPC + p];
    const float ebv = expb[lane];
    const float gC = g3[lane], bC = b3[lane];
    const float alpha = a2[0];
    const float cbv = cb2[lane];

    // stage hp2 rows for this tile (halo included)
    for (int e = tid; e < CPPC*ROWS; e += 256) {
        int p = e / ROWS, lr = e - p*ROWS;
        int f = f0 - 1 + lr;
        hb[p*FSTR + lr] = (f >= 0 && f < FR)
            ? hp2T[(size_t)p*(NN*FR) + (size_t)n*FR + f] : 0.0f;
    }
    __syncthreads();

    // x2 = x1 + silu(expand(hp2)); LN3 -> ys; x2 in registers
    float xreg[RPW];
    #pragma unroll
    for (int it = 0; it < RPW; ++it) {
        int lr = wid + it*4;
        int f  = f0 - 1 + lr;
        xreg[it] = 0.0f;
        if (lr < ROWS && f >= 0 && f < FR) {
            float z = ebv;
            #pragma unroll
            for (int p = 0; p < CPPC; ++p) z += hb[p*FSTR + lr] * ew[p];
            float sg = z / (1.0f + expf(-z));
            float v = x1[(size_t)n*FR*CC + (size_t)f*CC + lane] + sg;
            xreg[it] = v;
            float m, r; ln_stats(v, m, r);
            ys[lr*FSTR + lane] = (v - m) * r * gC + bC;
        }
    }
    __syncthreads();

    // conv2 + PReLU + residual -> out in [B, FR, TT, CC]
    const int gi = (lane >> 3) * CPG;
    const size_t ob0 = ((size_t)b*FR*TT + t)*CC;
    #pragma unroll
    for (int it = 0; it < RPW; ++it) {
        int lr = wid + it*4;
        int f  = f0 - 1 + lr;
        if (lr >= 1 && lr <= FT && f < FR) {
            float acc = cbv;
            if (f - 1 >= 0) {
                #pragma unroll
                for (int i = 0; i < CPG; ++i) acc += ys[(lr-1)*FSTR + gi + i] * wreg[i][0];
            }
            #pragma unroll
            for (int i = 0; i < CPG; ++i) acc += ys[lr*FSTR + gi + i] * wreg[i][1];
            if (f + 1 < FR) {
                #pragma unroll
                for (int i = 0; i < CPG; ++i) acc += ys[(lr+1)*FSTR + gi + i] * wreg[i][2];
            }
            float pr = acc >= 0.0f ? acc : alpha*acc;
            out[ob0 + (size_t)f*TT*CC + lane] = xreg[it] + pr;
        }
    }
}

extern "C" void kernel_launch(void* const* d_in, const int* in_sizes, int n_in,
                              void* d_out, int out_size, void* d_ws, size_t ws_size,
                              hipStream_t stream) {
    const float* h      = (const float*)d_in[0];
    const float* fc1_g  = (const float*)d_in[1];
    const float* fc1_b  = (const float*)d_in[2];
    const float* fc1_w  = (const float*)d_in[3];
    const float* fc1_cb = (const float*)d_in[4];
    const float* fc1_a  = (const float*)d_in[5];
    const float* fbl_g  = (const float*)d_in[6];
    const float* fbl_b  = (const float*)d_in[7];
    const float* red_w  = (const float*)d_in[8];
    const float* red_b  = (const float*)d_in[9];
    const float* fW     = (const float*)d_in[10];
    const float* fB     = (const float*)d_in[11];
    const float* exp_w  = (const float*)d_in[12];
    const float* exp_b  = (const float*)d_in[13];
    const float* fc2_g  = (const float*)d_in[14];
    const float* fc2_b  = (const float*)d_in[15];
    const float* fc2_w  = (const float*)d_in[16];
    const float* fc2_cb = (const float*)d_in[17];
    const float* fc2_a  = (const float*)d_in[18];

    float* ws   = (float*)d_ws;
    float* x1   = ws;
    float* hpT  = x1 + X1_ELEMS;
    float* hp2T = hpT + HP_ELEMS;

    dim3 g1(NN, NTIL);
    k_fc1<<<g1, 256, 0, stream>>>(h, fc1_g, fc1_b, fc1_w, fc1_cb, fc1_a,
                                  fbl_g, fbl_b, red_w, red_b, x1, hpT);

    dim3 g2((NN + BM - 1)/BM, (FR + BN - 1)/BN, CPPC);
    k_fgemm<<<g2, 256, 0, stream>>>(hpT, fW, fB, hp2T);

    dim3 g3(NN, NTIL);
    k_fc2<<<g3, 256, 0, stream>>>(x1, hp2T, exp_w, exp_b,
                                  fc2_g, fc2_b, fc2_w, fc2_cb, fc2_a,
                                  (float*)d_out);
}

// Round 3
// 1124.877 us; speedup vs baseline: 5.7119x; 5.7119x over previous
//
#include <hip/hip_runtime.h>
#include <math.h>

#define BDIM 8
#define FR   257
#define TT   300
#define CC   64
#define NN   (BDIM*TT)      // 2400
#define CPPC 16
#define GG   8
#define CPG  8              // CC/GG
#define KW   3
#define EPSV 1e-5f

#define FT    64            // inner rows per F-tile
#define NTIL  5             // ceil(257/64)
#define ROWS  66            // FT + 2 halo
#define FSTR  65            // LDS row stride: odd -> stride-65 reads conflict-free

#define X1_ELEMS ((size_t)NN*FR*CC)     // 39,475,200
#define HP_ELEMS ((size_t)CPPC*NN*FR)   //  9,868,800

__device__ __forceinline__ void ln_stats(float v, float& m, float& r) {
    float s = v, ss = v*v;
    #pragma unroll
    for (int off = 32; off > 0; off >>= 1) {
        s  += __shfl_xor(s,  off, 64);
        ss += __shfl_xor(ss, off, 64);
    }
    m = s * (1.0f/64.0f);
    float var = ss * (1.0f/64.0f) - m*m;
    r = rsqrtf(var + EPSV);
}

// ---------------- Kernel 1: LN1 + freq_conv1 + PReLU + res + LN2 + reduce + silu ----------------
__global__ __launch_bounds__(256, 4)
void k_fc1(const float* __restrict__ h,
           const float* __restrict__ g1, const float* __restrict__ b1,
           const float* __restrict__ w1, const float* __restrict__ cb1,
           const float* __restrict__ a1,
           const float* __restrict__ g2, const float* __restrict__ b2,
           const float* __restrict__ redw, const float* __restrict__ redb,
           float* __restrict__ x1, float* __restrict__ hpT)
{
    __shared__ float xs[ROWS*FSTR];   // residual row state
    __shared__ float ys[ROWS*FSTR];   // normalized row state

    const int n  = blockIdx.x;
    const int f0 = blockIdx.y * FT;
    const int nf = min(FT, FR - f0);
    const int b = n / TT, t = n - b*TT;
    const int tid = threadIdx.x;
    const int lane = tid & 63, wid = tid >> 6;

    float wreg[CPG][KW];
    #pragma unroll
    for (int i = 0; i < CPG; ++i)
        #pragma unroll
        for (int k = 0; k < KW; ++k)
            wreg[i][k] = w1[lane*CPG*KW + i*KW + k];
    const float alpha = a1[0];
    const float gA = g1[lane], bA = b1[lane];
    const float gB = g2[lane], bB = b2[lane];
    const float cbv = cb1[lane];

    // Phase A: load h rows (with halo) + LN1 -> ys; raw -> xs
    const size_t hb0 = ((size_t)b*FR*TT + t)*CC;
    for (int it = 0; it < 17; ++it) {
        int lr = wid + it*4;
        if (lr >= ROWS) break;
        int f = f0 - 1 + lr;
        if (f >= 0 && f < FR) {
            float v = h[hb0 + (size_t)f*TT*CC + lane];
            xs[lr*FSTR + lane] = v;
            float m, r; ln_stats(v, m, r);
            ys[lr*FSTR + lane] = (v - m) * r * gA + bA;
        } else {
            xs[lr*FSTR + lane] = 0.0f;
            ys[lr*FSTR + lane] = 0.0f;
        }
    }
    __syncthreads();

    // Phase B: grouped conv (K=3) + PReLU + residual on inner rows; x2 -> xs, x1 global
    const int gi = (lane >> 3) * CPG;
    for (int it = 0; it < 17; ++it) {
        int lr = 1 + wid + it*4;
        if (lr > nf) continue;
        int f = f0 + lr - 1;
        float acc = cbv;
        if (f - 1 >= 0) {
            #pragma unroll
            for (int i = 0; i < CPG; ++i) acc += ys[(lr-1)*FSTR + gi + i] * wreg[i][0];
        }
        #pragma unroll
        for (int i = 0; i < CPG; ++i) acc += ys[lr*FSTR + gi + i] * wreg[i][1];
        if (f + 1 < FR) {
            #pragma unroll
            for (int i = 0; i < CPG; ++i) acc += ys[(lr+1)*FSTR + gi + i] * wreg[i][2];
        }
        float pr = acc >= 0.0f ? acc : alpha*acc;
        float xv = xs[lr*FSTR + lane] + pr;
        xs[lr*FSTR + lane] = xv;          // same thread owns this slot
        x1[(size_t)n*FR*CC + (size_t)f*CC + lane] = xv;
    }
    __syncthreads();   // all conv reads of ys complete

    // Phase C: LN2 on inner rows -> ys
    for (int it = 0; it < 17; ++it) {
        int lr = 1 + wid + it*4;
        if (lr > nf) continue;
        float v = xs[lr*FSTR + lane];
        float m, r; ln_stats(v, m, r);
        ys[lr*FSTR + lane] = (v - m) * r * gB + bB;
    }
    __syncthreads();

    // Phase D: reduce to CPP=16 + silu. lane = inner row, wave owns 4 p's.
    // Weights are wave-uniform -> scalar loads (SMEM), LDS reads stride-65 (conflict-free).
    {
        const int L = lane;
        const int lr = (L < nf) ? (L + 1) : 1;
        const int p0 = wid * 4;
        const float* wp0 = redw + (size_t)(p0+0)*CC;
        const float* wp1 = redw + (size_t)(p0+1)*CC;
        const float* wp2 = redw + (size_t)(p0+2)*CC;
        const float* wp3 = redw + (size_t)(p0+3)*CC;
        float a0 = redb[p0+0], a1v = redb[p0+1], a2 = redb[p0+2], a3 = redb[p0+3];
        #pragma unroll 16
        for (int c = 0; c < CC; ++c) {
            float yv = ys[lr*FSTR + c];
            a0  += yv * wp0[c];
            a1v += yv * wp1[c];
            a2  += yv * wp2[c];
            a3  += yv * wp3[c];
        }
        if (L < nf) {
            int f = f0 + L;
            float s0 = a0  / (1.0f + expf(-a0));
            float s1 = a1v / (1.0f + expf(-a1v));
            float s2 = a2  / (1.0f + expf(-a2));
            float s3 = a3  / (1.0f + expf(-a3));
            size_t base = (size_t)n*FR + f;
            hpT[(size_t)(p0+0)*(NN*FR) + base] = s0;
            hpT[(size_t)(p0+1)*(NN*FR) + base] = s1;
            hpT[(size_t)(p0+2)*(NN*FR) + base] = s2;
            hpT[(size_t)(p0+3)*(NN*FR) + base] = s3;
        }
    }
}

// ---------------- Kernel 2: 16 batched GEMMs  out[n,f'] = sum_f A[n,f]*B[f',f] ----------------
#define BM 64
#define BN 64
#define BK 32
#define LDT 72

__global__ __launch_bounds__(256, 2)
void k_fgemm(const float* __restrict__ hpT, const float* __restrict__ fW,
             const float* __restrict__ fB, float* __restrict__ hp2T)
{
    __shared__ __align__(16) float As[BK*LDT];
    __shared__ __align__(16) float Bs[BK*LDT];
    const int c  = blockIdx.z;
    const int m0 = blockIdx.x * BM;
    const int f0 = blockIdx.y * BN;
    const int tid = threadIdx.x;
    const int tm = tid & 15, tn = tid >> 4;

    const float* Ab = hpT + (size_t)c*(NN*FR);
    const float* Bb = fW  + (size_t)c*(FR*FR);

    float acc[4][4];
    #pragma unroll
    for (int i = 0; i < 4; ++i)
        #pragma unroll
        for (int j = 0; j < 4; ++j) acc[i][j] = 0.0f;

    for (int k0 = 0; k0 < FR; k0 += BK) {
        #pragma unroll
        for (int l = 0; l < 8; ++l) {
            int e = tid + l*256;
            int r = e >> 5, kc = e & 31;
            int m = m0 + r, k = k0 + kc;
            As[kc*LDT + r] = (m < NN && k < FR) ? Ab[(size_t)m*FR + k] : 0.0f;
            int fr = f0 + r;
            Bs[kc*LDT + r] = (fr < FR && k < FR) ? Bb[(size_t)fr*FR + k] : 0.0f;
        }
        __syncthreads();
        #pragma unroll
        for (int k = 0; k < BK; ++k) {
            const float4 av = *reinterpret_cast<const float4*>(&As[k*LDT + (tm<<2)]);
            const float4 bv = *reinterpret_cast<const float4*>(&Bs[k*LDT + (tn<<2)]);
            acc[0][0] += av.x*bv.x; acc[0][1] += av.x*bv.y; acc[0][2] += av.x*bv.z; acc[0][3] += av.x*bv.w;
            acc[1][0] += av.y*bv.x; acc[1][1] += av.y*bv.y; acc[1][2] += av.y*bv.z; acc[1][3] += av.y*bv.w;
            acc[2][0] += av.z*bv.x; acc[2][1] += av.z*bv.y; acc[2][2] += av.z*bv.z; acc[2][3] += av.z*bv.w;
            acc[3][0] += av.w*bv.x; acc[3][1] += av.w*bv.y; acc[3][2] += av.w*bv.z; acc[3][3] += av.w*bv.w;
        }
        __syncthreads();
    }

    #pragma unroll
    for (int i = 0; i < 4; ++i) {
        int m = m0 + (tm<<2) + i;
        if (m >= NN) continue;
        #pragma unroll
        for (int j = 0; j < 4; ++j) {
            int fr = f0 + (tn<<2) + j;
            if (fr < FR)
                hp2T[(size_t)c*(NN*FR) + (size_t)m*FR + fr] = acc[i][j] + fB[c*FR + fr];
        }
    }
}

// ---------------- Kernel 3: expand + silu + residual + LN3 + freq_conv2 ----------------
__global__ __launch_bounds__(256, 4)
void k_fc2(const float* __restrict__ x1, const float* __restrict__ hp2T,
           const float* __restrict__ expw, const float* __restrict__ expb,
           const float* __restrict__ g3, const float* __restrict__ b3,
           const float* __restrict__ w2, const float* __restrict__ cb2,
           const float* __restrict__ a2,
           float* __restrict__ out)
{
    __shared__ float xs[ROWS*FSTR];
    __shared__ float ys[ROWS*FSTR];

    const int n  = blockIdx.x;
    const int f0 = blockIdx.y * FT;
    const int nf = min(FT, FR - f0);
    const int b = n / TT, t = n - b*TT;
    const int tid = threadIdx.x;
    const int lane = tid & 63, wid = tid >> 6;

    float wreg[CPG][KW];
    #pragma unroll
    for (int i = 0; i < CPG; ++i)
        #pragma unroll
        for (int k = 0; k < KW; ++k)
            wreg[i][k] = w2[lane*CPG*KW + i*KW + k];
    float ew[CPPC];
    #pragma unroll
    for (int p = 0; p < CPPC; ++p) ew[p] = expw[lane*CPPC + p];
    const float ebv = expb[lane];
    const float gC = g3[lane], bC = b3[lane];
    const float alpha = a2[0];
    const float cbv = cb2[lane];

    // Phase A: x2 = x1 + silu(expand(hp2)) for all rows (halo incl); LN3 -> ys
    // hp2T values are wave-uniform per row -> scalar loads, no LDS staging.
    for (int it = 0; it < 17; ++it) {
        int lr = wid + it*4;
        if (lr >= ROWS) break;
        int f = f0 - 1 + lr;
        if (f >= 0 && f < FR) {
            size_t base = (size_t)n*FR + f;
            float z = ebv;
            #pragma unroll
            for (int p = 0; p < CPPC; ++p)
                z += hp2T[(size_t)p*(NN*FR) + base] * ew[p];
            float sg = z / (1.0f + expf(-z));
            float v = x1[(size_t)n*FR*CC + (size_t)f*CC + lane] + sg;
            xs[lr*FSTR + lane] = v;
            float m, r; ln_stats(v, m, r);
            ys[lr*FSTR + lane] = (v - m) * r * gC + bC;
        } else {
            xs[lr*FSTR + lane] = 0.0f;
            ys[lr*FSTR + lane] = 0.0f;
        }
    }
    __syncthreads();

    // Phase B: conv2 + PReLU + residual -> out in [B, FR, TT, CC]
    const int gi = (lane >> 3) * CPG;
    const size_t ob0 = ((size_t)b*FR*TT + t)*CC;
    for (int it = 0; it < 17; ++it) {
        int lr = 1 + wid + it*4;
        if (lr > nf) continue;
        int f = f0 + lr - 1;
        float acc = cbv;
        if (f - 1 >= 0) {
            #pragma unroll
            for (int i = 0; i < CPG; ++i) acc += ys[(lr-1)*FSTR + gi + i] * wreg[i][0];
        }
        #pragma unroll
        for (int i = 0; i < CPG; ++i) acc += ys[lr*FSTR + gi + i] * wreg[i][1];
        if (f + 1 < FR) {
            #pragma unroll
            for (int i = 0; i < CPG; ++i) acc += ys[(lr+1)*FSTR + gi + i] * wreg[i][2];
        }
        float pr = acc >= 0.0f ? acc : alpha*acc;
        out[ob0 + (size_t)f*TT*CC + lane] = xs[lr*FSTR + lane] + pr;
    }
}

extern "C" void kernel_launch(void* const* d_in, const int* in_sizes, int n_in,
                              void* d_out, int out_size, void* d_ws, size_t ws_size,
                              hipStream_t stream) {
    const float* h      = (const float*)d_in[0];
    const float* fc1_g  = (const float*)d_in[1];
    const float* fc1_b  = (const float*)d_in[2];
    const float* fc1_w  = (const float*)d_in[3];
    const float* fc1_cb = (const float*)d_in[4];
    const float* fc1_a  = (const float*)d_in[5];
    const float* fbl_g  = (const float*)d_in[6];
    const float* fbl_b  = (const float*)d_in[7];
    const float* red_w  = (const float*)d_in[8];
    const float* red_b  = (const float*)d_in[9];
    const float* fW     = (const float*)d_in[10];
    const float* fB     = (const float*)d_in[11];
    const float* exp_w  = (const float*)d_in[12];
    const float* exp_b  = (const float*)d_in[13];
    const float* fc2_g  = (const float*)d_in[14];
    const float* fc2_b  = (const float*)d_in[15];
    const float* fc2_w  = (const float*)d_in[16];
    const float* fc2_cb = (const float*)d_in[17];
    const float* fc2_a  = (const float*)d_in[18];

    float* ws   = (float*)d_ws;
    float* x1   = ws;
    float* hpT  = x1 + X1_ELEMS;
    float* hp2T = hpT + HP_ELEMS;

    dim3 g1(NN, NTIL);
    k_fc1<<<g1, 256, 0, stream>>>(h, fc1_g, fc1_b, fc1_w, fc1_cb, fc1_a,
                                  fbl_g, fbl_b, red_w, red_b, x1, hpT);

    dim3 g2((NN + BM - 1)/BM, (FR + BN - 1)/BN, CPPC);
    k_fgemm<<<g2, 256, 0, stream>>>(hpT, fW, fB, hp2T);

    dim3 g3(NN, NTIL);
    k_fc2<<<g3, 256, 0, stream>>>(x1, hp2T, exp_w, exp_b,
                                  fc2_g, fc2_b, fc2_w, fc2_cb, fc2_a,
                                  (float*)d_out);
}